// Round 2
// baseline (342.485 us; speedup 1.0000x reference)
//
#include <hip/hip_runtime.h>
#include <hip/hip_bf16.h>
#include <stdint.h>

// Problem: out = x_norm + dropout(relu(LN(x) @ W1) @ W2), B=4,S=2048,D=2048
#define M_DIM 8192   // B*S
#define N_DIM 2048
#define K_DIM 2048

typedef __bf16 bf16x8_t __attribute__((ext_vector_type(8)));
typedef float f32x4_t __attribute__((ext_vector_type(4)));

// ---------------- threefry2x32, JAX partitionable path, key=(0,1) -------------
// bits(j) = o0^o1 of threefry2x32(key=(0,1), ctr=(0, j)); keep iff bits < 0xC0000000.
// Verified: absmax 0.0625 -> mask exact.
__device__ __forceinline__ unsigned tf_rotl(unsigned x, int r) {
  return (x << r) | (x >> (32 - r));
}
__device__ __forceinline__ unsigned threefry_mask_bits(unsigned ctr) {
  unsigned x0 = 0u, x1 = ctr;
  const unsigned ks0 = 0u, ks1 = 1u, ks2 = 0x1BD11BDBu;
  x0 += ks0; x1 += ks1;
#define TFR(r) { x0 += x1; x1 = tf_rotl(x1, (r)); x1 ^= x0; }
  TFR(13) TFR(15) TFR(26) TFR(6)
  x0 += ks1; x1 += ks2 + 1u;
  TFR(17) TFR(29) TFR(16) TFR(24)
  x0 += ks2; x1 += ks0 + 2u;
  TFR(13) TFR(15) TFR(26) TFR(6)
  x0 += ks0; x1 += ks1 + 3u;
  TFR(17) TFR(29) TFR(16) TFR(24)
  x0 += ks1; x1 += ks2 + 4u;
  TFR(13) TFR(15) TFR(26) TFR(6)
  x0 += ks2; x1 += ks0 + 5u;
#undef TFR
  return x0 ^ x1;
}

// ---------------- async global->LDS, 16B per lane -----------------------------
__device__ __forceinline__ void gload_lds16(const __hip_bfloat16* g, unsigned short* l) {
  __builtin_amdgcn_global_load_lds(
      (const __attribute__((address_space(1))) unsigned int*)g,
      (__attribute__((address_space(3))) unsigned int*)l,
      16, 0, 0);
}

// ---------------- W [K][N] fp32 -> Wt [N][K] bf16 -----------------------------
__global__ __launch_bounds__(256) void wt_kernel(
    const float* __restrict__ W1, const float* __restrict__ W2,
    __hip_bfloat16* __restrict__ W1t, __hip_bfloat16* __restrict__ W2t) {
  __shared__ float tile[32][33];
  const float* src = blockIdx.z ? W2 : W1;
  __hip_bfloat16* dst = blockIdx.z ? W2t : W1t;
  int x = blockIdx.x * 32 + threadIdx.x;
  int y = blockIdx.y * 32 + threadIdx.y;
#pragma unroll
  for (int i = 0; i < 32; i += 8)
    tile[threadIdx.y + i][threadIdx.x] = src[(size_t)(y + i) * N_DIM + x];
  __syncthreads();
  int xo = blockIdx.y * 32 + threadIdx.x;
  int yo = blockIdx.x * 32 + threadIdx.y;
#pragma unroll
  for (int i = 0; i < 32; i += 8)
    dst[(size_t)(yo + i) * K_DIM + xo] = __float2bfloat16(tile[threadIdx.x][threadIdx.y + i]);
}

// ---------------- LayerNorm (no affine) -> bf16 -------------------------------
__global__ __launch_bounds__(256) void ln_kernel(const float* __restrict__ X,
                                                 __hip_bfloat16* __restrict__ Xn) {
  const int row = blockIdx.x;
  const float4* xv = (const float4*)(X + (size_t)row * K_DIM);
  float4 v0 = xv[threadIdx.x];
  float4 v1 = xv[threadIdx.x + 256];
  float s  = v0.x + v0.y + v0.z + v0.w + v1.x + v1.y + v1.z + v1.w;
  float ss = v0.x*v0.x + v0.y*v0.y + v0.z*v0.z + v0.w*v0.w
           + v1.x*v1.x + v1.y*v1.y + v1.z*v1.z + v1.w*v1.w;
#pragma unroll
  for (int off = 32; off > 0; off >>= 1) {
    s  += __shfl_xor(s, off);
    ss += __shfl_xor(ss, off);
  }
  __shared__ float rs[4], rss[4];
  const int wave = threadIdx.x >> 6;
  if ((threadIdx.x & 63) == 0) { rs[wave] = s; rss[wave] = ss; }
  __syncthreads();
  float S  = rs[0] + rs[1] + rs[2] + rs[3];
  float SS = rss[0] + rss[1] + rss[2] + rss[3];
  float mean = S * (1.0f / 2048.0f);
  float var  = SS * (1.0f / 2048.0f) - mean * mean;
  float rstd = 1.0f / sqrtf(var + 1e-6f);
  float vv[8] = {v0.x, v0.y, v0.z, v0.w, v1.x, v1.y, v1.z, v1.w};
  unsigned short o[8];
#pragma unroll
  for (int i = 0; i < 8; i++) {
    __hip_bfloat16 b = __float2bfloat16((vv[i] - mean) * rstd);
    o[i] = *(unsigned short*)&b;
  }
  ushort4* dst = (ushort4*)(Xn + (size_t)row * K_DIM);
  dst[threadIdx.x]       = make_ushort4(o[0], o[1], o[2], o[3]);
  dst[threadIdx.x + 256] = make_ushort4(o[4], o[5], o[6], o[7]);
}

// ---------------- 256x256 MFMA GEMM, BK=64, 8-phase counted-vmcnt schedule ----
// A[M][K], Bt[N][K] bf16. 512 threads = 8 waves (2M x 4N), per-wave 128x64 out.
// LDS: 2 x (A 256x64 + B 256x64) bf16 = 128 KB, double-buffered by K-tile.
// LDS rows are 64 elems (128 B); 16B-chunk slot s of row r holds global chunk
// s^(r&7): pre-swizzled global source + swizzled ds_read addr (both-sides rule).
// Same read pattern as the verified 128^2 kernel (measured 0 bank conflicts).
// Per K-tile: 4 phases, each {ds_read subtile; issue 1 half-tile (2 gload_lds);
// s_barrier; lgkmcnt(0)+sched_barrier(0); setprio(1); 16 MFMA; setprio(0); bar}.
// Staging runs 3 half-tiles ahead: phase1 -> B-late(t+1) (other buffer),
// phases2-4 -> A-early/B-early/A-late(t+2) (current buffer; each region's
// readers completed one barrier earlier:
//   A-early rows {0-63,128-191}  read only in phase 1,
//   B-early rows {(n&63)<32}     read only in phase 1,
//   B-late                        read in phase 2,
//   A-late rows {64-127,192-255} read in phase 3).
// vmcnt(6) once per tile (phase 4) = 3 half-tiles in flight; tile t+1 buffer
// guaranteed complete at entry. Drain vmcnt(0) only at tile 30. Raw s_barrier
// throughout -- __syncthreads would drain vmcnt and kill the pipeline.
// Rule #18 hardening: sched_barrier(0) after every lgkmcnt(0) so MFMA cannot
// be hoisted above the wait (hipcc does this despite the "memory" clobber).
// EPI=0: H=relu(A@B)->bf16. EPI=1: out=Xn+dropout(A@B)/0.75.
template <int EPI>
__global__ __launch_bounds__(512, 2) void gemm256(
    const __hip_bfloat16* __restrict__ A,
    const __hip_bfloat16* __restrict__ Bt,
    const __hip_bfloat16* __restrict__ Xn,   // EPI=1 residual
    __hip_bfloat16* __restrict__ Hout,       // EPI=0 output
    float* __restrict__ Fout) {              // EPI=1 output
  __shared__ unsigned short As[2][16384];  // 2 x 32 KB
  __shared__ unsigned short Bs[2][16384];  // 2 x 32 KB
  const int tid  = threadIdx.x;
  const int lane = tid & 63;
  const int wave = tid >> 6;      // 0..7
  const int wm = wave >> 2;       // 0..1 (M)
  const int wn = wave & 3;        // 0..3 (N)

  // XCD-aware swizzle: nwg=256 (divisible by 8) -> XCD x owns logical wgs
  // x*32..x*32+31 = all 32 M-tiles of one N-column -> 1 MB B panel L2-resident.
  const int bid = blockIdx.x;
  const int wg  = (bid & 7) * 32 + (bid >> 3);
  const int mBase = (wg & 31) << 8;   // 32 M-tiles, fastest
  const int nBase = (wg >> 5) << 8;   // 8 N-tiles

  f32x4_t acc[8][4];
#pragma unroll
  for (int i = 0; i < 8; i++)
#pragma unroll
    for (int j = 0; j < 4; j++) acc[i][j] = (f32x4_t){0.f, 0.f, 0.f, 0.f};

  // ---- staging addresses. Half-tile = 128 rows x 128 B = 2 gloads/thread.
  // Wave w covers 8 rows/gload; lane l: row l>>3, source chunk (l&7)^(row&7).
  const int rowIn = lane >> 3;
  const int csrc  = ((lane & 7) ^ (rowIn & 7)) << 3;   // swizzled src elem offset
  const __hip_bfloat16* aSrcB = A  + (size_t)(mBase + 8 * wave + rowIn) * K_DIM + csrc;
  const int bRowW = ((wave >> 2) << 6) + ((wave & 3) << 3);
  const __hip_bfloat16* bSrcB = Bt + (size_t)(nBase + bRowW + rowIn) * K_DIM + csrc;
  const int aDst = wave << 9;     // shorts; wave-uniform base, HW adds lane*16B
  const int bDst = bRowW << 6;

  // A half h: rows h*64 + 128j + 8w + rowIn  (h=0 early, h=1 late)
  // B half h: rows h*32 + 128j + bRowW + rowIn
#define STA(b, h, k)                                                                         \
  gload_lds16(aSrcB + (size_t)((h) * 64) * K_DIM + (k), &As[b][aDst + (h) * 4096]);          \
  gload_lds16(aSrcB + (size_t)((h) * 64 + 128) * K_DIM + (k), &As[b][aDst + (h) * 4096 + 8192]);
#define STB(b, h, k)                                                                         \
  gload_lds16(bSrcB + (size_t)((h) * 32) * K_DIM + (k), &Bs[b][bDst + (h) * 2048]);          \
  gload_lds16(bSrcB + (size_t)((h) * 32 + 128) * K_DIM + (k), &Bs[b][bDst + (h) * 2048 + 8192]);

  // ---- fragment read addresses (static swizzle: slot = chunk ^ (row&7))
  const int fr = lane & 15;
  const int fq = lane >> 4;
  const int c0 = ((fq)     ^ (fr & 7)) << 3;   // kk=0 chunk offset (shorts)
  const int c1 = ((4 | fq) ^ (fr & 7)) << 3;   // kk=1 chunk offset
  const int aRd = (wm * 128 + fr) * 64;
  const int bRd = (wn * 64  + fr) * 64;

  bf16x8_t aF[4][2], bF[4][2];
#define RDA(b, f)                                                      \
  aF[(f) & 3][0] = *(const bf16x8_t*)&As[b][aRd + (f) * 1024 + c0];    \
  aF[(f) & 3][1] = *(const bf16x8_t*)&As[b][aRd + (f) * 1024 + c1];
#define RDB(b, nf)                                                     \
  bF[nf][0] = *(const bf16x8_t*)&Bs[b][bRd + (nf) * 1024 + c0];        \
  bF[nf][1] = *(const bf16x8_t*)&Bs[b][bRd + (nf) * 1024 + c1];

#define MFMAQ(mh, nlo)                                                             \
  _Pragma("unroll")                                                                \
  for (int mi = 0; mi < 4; mi++) {                                                 \
    _Pragma("unroll")                                                              \
    for (int nj = 0; nj < 2; nj++) {                                               \
      acc[(mh) * 4 + mi][(nlo) + nj] = __builtin_amdgcn_mfma_f32_16x16x32_bf16(    \
          aF[mi][0], bF[(nlo) + nj][0], acc[(mh) * 4 + mi][(nlo) + nj], 0, 0, 0);  \
      acc[(mh) * 4 + mi][(nlo) + nj] = __builtin_amdgcn_mfma_f32_16x16x32_bf16(    \
          aF[mi][1], bF[(nlo) + nj][1], acc[(mh) * 4 + mi][(nlo) + nj], 0, 0, 0);  \
    }                                                                              \
  }

#define BAR() __builtin_amdgcn_s_barrier()
#define LGKM0()                                              \
  {                                                          \
    asm volatile("s_waitcnt lgkmcnt(0)" ::: "memory");       \
    __builtin_amdgcn_sched_barrier(0);                       \
  }
#define LGKM8() asm volatile("s_waitcnt lgkmcnt(8)" ::: "memory")
#define VMW(n)                                               \
  {                                                          \
    asm volatile("s_waitcnt vmcnt(" #n ")" ::: "memory");    \
    __builtin_amdgcn_sched_barrier(0);                       \
  }

  // TILE(t): 4 phases. S1..S4 enable the stage of each phase; VMODE 0=vmcnt(6),
  // 1=vmcnt(0) (drain), 2=none.
#define TILE(t, S1, S2, S3, S4, VMODE)                                   \
  {                                                                      \
    const int buf = (t) & 1;                                             \
    /* phase 1: quadrant (m0-3, n0-1); stage B-late(t+1) -> other buf */ \
    RDA(buf, 0) RDA(buf, 1) RDA(buf, 2) RDA(buf, 3)                      \
    RDB(buf, 0) RDB(buf, 1)                                              \
    if (S1) { STB(buf ^ 1, 1, ((t) + 1) * 64) }                          \
    LGKM8(); BAR(); LGKM0();                                             \
    __builtin_amdgcn_s_setprio(1); MFMAQ(0, 0)                           \
    __builtin_amdgcn_s_setprio(0); BAR();                                \
    /* phase 2: quadrant (m0-3, n2-3); stage A-early(t+2) -> this buf */ \
    RDB(buf, 2) RDB(buf, 3)                                              \
    if (S2) { STA(buf, 0, ((t) + 2) * 64) }                              \
    BAR(); LGKM0();                                                      \
    __builtin_amdgcn_s_setprio(1); MFMAQ(0, 2)                           \
    __builtin_amdgcn_s_setprio(0); BAR();                                \
    /* phase 3: quadrant (m4-7, n0-1); stage B-early(t+2) -> this buf */ \
    RDA(buf, 4) RDA(buf, 5) RDA(buf, 6) RDA(buf, 7)                      \
    if (S3) { STB(buf, 0, ((t) + 2) * 64) }                              \
    BAR(); LGKM0();                                                      \
    __builtin_amdgcn_s_setprio(1); MFMAQ(1, 0)                           \
    __builtin_amdgcn_s_setprio(0); BAR();                                \
    /* phase 4: quadrant (m4-7, n2-3); stage A-late(t+2); counted wait */\
    if (S4) { STA(buf, 1, ((t) + 2) * 64) }                              \
    if ((VMODE) == 0) { VMW(6); } else if ((VMODE) == 1) { VMW(0); }     \
    BAR();                                                               \
    __builtin_amdgcn_s_setprio(1); MFMAQ(1, 2)                           \
    __builtin_amdgcn_s_setprio(0); BAR();                                \
  }

  // ---- prologue: tile0 (4 halves) + tile1 first 3 halves, counted waits.
  STA(0, 0, 0) STB(0, 0, 0) STA(0, 1, 0) STB(0, 1, 0)
  VMW(4);
  STA(1, 0, 64) STB(1, 0, 64) STA(1, 1, 64)
  VMW(6);              // tile 0 fully landed (14 issued, <=6 outstanding)
  BAR();

  // nt = 32 K-tiles. Full pipeline for t<30; t=30 stages only B-late(31) and
  // drains; t=31 computes from LDS only.
  for (int t = 0; t < 30; ++t) {
    TILE(t, 1, 1, 1, 1, 0)
  }
  TILE(30, 1, 0, 0, 0, 1)
  TILE(31, 0, 0, 0, 0, 2)

#undef TILE
#undef STA
#undef STB
#undef RDA
#undef RDB
#undef MFMAQ
#undef BAR
#undef LGKM0
#undef LGKM8
#undef VMW

  // epilogue: D row = fq*4 + r, col = fr (m89-verified C/D layout)
  const int mW = mBase + wm * 128 + fq * 4;
  const int nW = nBase + wn * 64 + fr;
#pragma unroll
  for (int f = 0; f < 8; f++) {
#pragma unroll
    for (int nf = 0; nf < 4; nf++) {
      const int n  = nW + nf * 16;
      const int m0 = mW + f * 16;
#pragma unroll
      for (int r = 0; r < 4; r++) {
        float v = acc[f][nf][r];
        size_t j = (size_t)(m0 + r) * N_DIM + n;
        if (EPI == 0) {
          Hout[j] = __float2bfloat16(fmaxf(v, 0.0f));
        } else {
          unsigned bits = threefry_mask_bits((unsigned)j);
          float y  = (bits < 0xC0000000u) ? v * (1.0f / 0.75f) : 0.0f;
          Fout[j]  = __bfloat162float(Xn[j]) + y;
        }
      }
    }
  }
}

extern "C" void kernel_launch(void* const* d_in, const int* in_sizes, int n_in,
                              void* d_out, int out_size, void* d_ws, size_t ws_size,
                              hipStream_t stream) {
  (void)in_sizes; (void)n_in; (void)out_size; (void)ws_size;
  const float* X  = (const float*)d_in[0];
  const float* W1 = (const float*)d_in[1];
  const float* W2 = (const float*)d_in[2];
  float* out = (float*)d_out;

  unsigned char* ws = (unsigned char*)d_ws;
  __hip_bfloat16* Xn  = (__hip_bfloat16*)(ws);                       // 32 MB
  __hip_bfloat16* H   = (__hip_bfloat16*)(ws + ((size_t)32 << 20));  // 32 MB
  __hip_bfloat16* W1t = (__hip_bfloat16*)(ws + ((size_t)64 << 20));  //  8 MB
  __hip_bfloat16* W2t = (__hip_bfloat16*)(ws + ((size_t)72 << 20));  //  8 MB

  wt_kernel<<<dim3(64, 64, 2), dim3(32, 8, 1), 0, stream>>>(W1, W2, W1t, W2t);
  ln_kernel<<<M_DIM, 256, 0, stream>>>(X, Xn);
  gemm256<0><<<dim3(256, 1, 1), dim3(512, 1, 1), 0, stream>>>(Xn, W1t, nullptr, H, nullptr);
  gemm256<1><<<dim3(256, 1, 1), dim3(512, 1, 1), 0, stream>>>(H, W2t, Xn, nullptr, out);
}

// Round 3
// 342.064 us; speedup vs baseline: 1.0012x; 1.0012x over previous
//
#include <hip/hip_runtime.h>
#include <hip/hip_bf16.h>
#include <stdint.h>

// Problem: out = x_norm + dropout(relu(LN(x) @ W1) @ W2), B=4,S=2048,D=2048
#define M_DIM 8192   // B*S
#define N_DIM 2048
#define K_DIM 2048

typedef __bf16 bf16x8_t __attribute__((ext_vector_type(8)));
typedef float f32x4_t __attribute__((ext_vector_type(4)));

// ---------------- threefry2x32, JAX partitionable path, key=(0,1) -------------
// bits(j) = o0^o1 of threefry2x32(key=(0,1), ctr=(0, j)); keep iff bits < 0xC0000000.
// Verified: absmax 0.0625 -> mask exact.
__device__ __forceinline__ unsigned tf_rotl(unsigned x, int r) {
  return (x << r) | (x >> (32 - r));
}
__device__ __forceinline__ unsigned threefry_mask_bits(unsigned ctr) {
  unsigned x0 = 0u, x1 = ctr;
  const unsigned ks0 = 0u, ks1 = 1u, ks2 = 0x1BD11BDBu;
  x0 += ks0; x1 += ks1;
#define TFR(r) { x0 += x1; x1 = tf_rotl(x1, (r)); x1 ^= x0; }
  TFR(13) TFR(15) TFR(26) TFR(6)
  x0 += ks1; x1 += ks2 + 1u;
  TFR(17) TFR(29) TFR(16) TFR(24)
  x0 += ks2; x1 += ks0 + 2u;
  TFR(13) TFR(15) TFR(26) TFR(6)
  x0 += ks0; x1 += ks1 + 3u;
  TFR(17) TFR(29) TFR(16) TFR(24)
  x0 += ks1; x1 += ks2 + 4u;
  TFR(13) TFR(15) TFR(26) TFR(6)
  x0 += ks2; x1 += ks0 + 5u;
#undef TFR
  return x0 ^ x1;
}

// ---------------- async global->LDS, 16B per lane -----------------------------
__device__ __forceinline__ void gload_lds16(const __hip_bfloat16* g, unsigned short* l) {
  __builtin_amdgcn_global_load_lds(
      (const __attribute__((address_space(1))) unsigned int*)g,
      (__attribute__((address_space(3))) unsigned int*)l,
      16, 0, 0);
}

// ---------------- W [K][N] fp32 -> Wt [N][K] bf16 -----------------------------
__global__ __launch_bounds__(256) void wt_kernel(
    const float* __restrict__ W1, const float* __restrict__ W2,
    __hip_bfloat16* __restrict__ W1t, __hip_bfloat16* __restrict__ W2t) {
  __shared__ float tile[32][33];
  const float* src = blockIdx.z ? W2 : W1;
  __hip_bfloat16* dst = blockIdx.z ? W2t : W1t;
  int x = blockIdx.x * 32 + threadIdx.x;
  int y = blockIdx.y * 32 + threadIdx.y;
#pragma unroll
  for (int i = 0; i < 32; i += 8)
    tile[threadIdx.y + i][threadIdx.x] = src[(size_t)(y + i) * N_DIM + x];
  __syncthreads();
  int xo = blockIdx.y * 32 + threadIdx.x;
  int yo = blockIdx.x * 32 + threadIdx.y;
#pragma unroll
  for (int i = 0; i < 32; i += 8)
    dst[(size_t)(yo + i) * K_DIM + xo] = __float2bfloat16(tile[threadIdx.x][threadIdx.y + i]);
}

// ---------------- LayerNorm (no affine) -> bf16 -------------------------------
__global__ __launch_bounds__(256) void ln_kernel(const float* __restrict__ X,
                                                 __hip_bfloat16* __restrict__ Xn) {
  const int row = blockIdx.x;
  const float4* xv = (const float4*)(X + (size_t)row * K_DIM);
  float4 v0 = xv[threadIdx.x];
  float4 v1 = xv[threadIdx.x + 256];
  float s  = v0.x + v0.y + v0.z + v0.w + v1.x + v1.y + v1.z + v1.w;
  float ss = v0.x*v0.x + v0.y*v0.y + v0.z*v0.z + v0.w*v0.w
           + v1.x*v1.x + v1.y*v1.y + v1.z*v1.z + v1.w*v1.w;
#pragma unroll
  for (int off = 32; off > 0; off >>= 1) {
    s  += __shfl_xor(s, off);
    ss += __shfl_xor(ss, off);
  }
  __shared__ float rs[4], rss[4];
  const int wave = threadIdx.x >> 6;
  if ((threadIdx.x & 63) == 0) { rs[wave] = s; rss[wave] = ss; }
  __syncthreads();
  float S  = rs[0] + rs[1] + rs[2] + rs[3];
  float SS = rss[0] + rss[1] + rss[2] + rss[3];
  float mean = S * (1.0f / 2048.0f);
  float var  = SS * (1.0f / 2048.0f) - mean * mean;
  float rstd = 1.0f / sqrtf(var + 1e-6f);
  float vv[8] = {v0.x, v0.y, v0.z, v0.w, v1.x, v1.y, v1.z, v1.w};
  unsigned short o[8];
#pragma unroll
  for (int i = 0; i < 8; i++) {
    __hip_bfloat16 b = __float2bfloat16((vv[i] - mean) * rstd);
    o[i] = *(unsigned short*)&b;
  }
  ushort4* dst = (ushort4*)(Xn + (size_t)row * K_DIM);
  dst[threadIdx.x]       = make_ushort4(o[0], o[1], o[2], o[3]);
  dst[threadIdx.x + 256] = make_ushort4(o[4], o[5], o[6], o[7]);
}

// ---------------- 256x256 MFMA GEMM, BK=64, 8-phase counted-vmcnt schedule ----
// A[M][K], Bt[N][K] bf16. 512 threads = 8 waves (2M x 4N), per-wave 128x64 out.
// LDS: 2 x (A 256x64 + B 256x64) bf16 = 128 KB, double-buffered by K-tile.
// Round-2 post-mortem: phase split by (m-half, n-pair) held aF+bF (64 VGPR)
// live across barriers -> arch regs hit the 256-unified cap (acc=128 AGPR)
// -> per-iteration scratch spills (262 MB WRITE_SIZE, 3.1 TB/s, MfmaUtil 19%).
// This version splits phases by (m-half, kk): per phase 4 A-frags (phase-local,
// 16 VGPR) + 4 B-frags per kk (bK0 live ph1->ph3, bK1 ph2->ph4). Peak frag
// liveness 48 VGPR; 24 ds_read_b128/tile (same as proven m201 ratio). K-loop
// unrolled by 2 so buf is a literal -> all LDS addrs are base+imm (<64 KB).
// Region/reader map (kk split => every B row read every phase):
//   A-early rows {0-63,128-191}: read ph1,ph2  -> stage(t+2) at ph3 (cur buf)
//   A-late  rows {64-127,192-255}: read ph3,ph4 -> stage(t+1) at ph1 (other buf)
//   B (all rows): read every phase             -> stage(t+1) at ph1 (other buf)
// Issues: ph1 6 gloads, ph3 2 gloads. VMW(2) at ph4 leaves only ph3's
// A-early(t+2) in flight => everything tile t+1 reads is complete before the
// ph4 trailing barrier. Drain vmcnt(0) only at t=30. Raw s_barrier throughout;
// sched_barrier(0) after each lgkmcnt(0) (rule #18). Per-acc-element MFMA
// order still kk0 then kk1 per tile -> bit-identical to the 110 us kernel.
// EPI=0: H=relu(A@B)->bf16. EPI=1: out=Xn+dropout(A@B)/0.75.
template <int EPI>
__global__ __launch_bounds__(512, 2) void gemm256(
    const __hip_bfloat16* __restrict__ A,
    const __hip_bfloat16* __restrict__ Bt,
    const __hip_bfloat16* __restrict__ Xn,   // EPI=1 residual
    __hip_bfloat16* __restrict__ Hout,       // EPI=0 output
    float* __restrict__ Fout) {              // EPI=1 output
  __shared__ unsigned short As[2][16384];  // 2 x 32 KB
  __shared__ unsigned short Bs[2][16384];  // 2 x 32 KB
  const int tid  = threadIdx.x;
  const int lane = tid & 63;
  const int wave = tid >> 6;      // 0..7
  const int wm = wave >> 2;       // 0..1 (M)
  const int wn = wave & 3;        // 0..3 (N)

  // XCD-aware swizzle: nwg=256 (divisible by 8) -> XCD x owns all 32 M-tiles
  // of one N-column -> 1 MB B panel L2-resident per XCD.
  const int bid = blockIdx.x;
  const int wg  = (bid & 7) * 32 + (bid >> 3);
  const int mBase = (wg & 31) << 8;   // 32 M-tiles, fastest
  const int nBase = (wg >> 5) << 8;   // 8 N-tiles

  f32x4_t acc[8][4];
#pragma unroll
  for (int i = 0; i < 8; i++)
#pragma unroll
    for (int j = 0; j < 4; j++) acc[i][j] = (f32x4_t){0.f, 0.f, 0.f, 0.f};

  // ---- staging addresses. Half-tile = 128 rows x 128 B = 2 gloads/thread.
  // Wave w covers 8 rows/gload; lane l: row l>>3, source chunk (l&7)^(row&7).
  const int rowIn = lane >> 3;
  const int csrc  = ((lane & 7) ^ (rowIn & 7)) << 3;   // swizzled src elem offset
  const __hip_bfloat16* aSrcB = A  + (size_t)(mBase + 8 * wave + rowIn) * K_DIM + csrc;
  const int bRowW = ((wave >> 2) << 6) + ((wave & 3) << 3);
  const __hip_bfloat16* bSrcB = Bt + (size_t)(nBase + bRowW + rowIn) * K_DIM + csrc;
  const int aDst = wave << 9;     // shorts; wave-uniform base, HW adds lane*16B
  const int bDst = bRowW << 6;

  // A half h: rows h*64 + {0,128} + 8w + rowIn  (h=0 early, h=1 late)
  // B half h: rows h*32 + {0,128} + bRowW + rowIn
#define STA(b, h, k)                                                                         \
  gload_lds16(aSrcB + (size_t)((h) * 64) * K_DIM + (k), &As[b][aDst + (h) * 4096]);          \
  gload_lds16(aSrcB + (size_t)((h) * 64 + 128) * K_DIM + (k), &As[b][aDst + (h) * 4096 + 8192]);
#define STB(b, h, k)                                                                         \
  gload_lds16(bSrcB + (size_t)((h) * 32) * K_DIM + (k), &Bs[b][bDst + (h) * 2048]);          \
  gload_lds16(bSrcB + (size_t)((h) * 32 + 128) * K_DIM + (k), &Bs[b][bDst + (h) * 2048 + 8192]);

  // ---- fragment read addresses (static swizzle: slot = chunk ^ (row&7))
  const int fr = lane & 15;
  const int fq = lane >> 4;
  const int ck0 = ((fq)     ^ (fr & 7)) << 3;   // kk=0 chunk offset (shorts)
  const int ck1 = ((4 | fq) ^ (fr & 7)) << 3;   // kk=1 chunk offset
  const int aRd = (wm * 128 + fr) * 64;
  const int bRd = (wn * 64  + fr) * 64;

  bf16x8_t aF[4];        // per-phase A fragments (phase-local)
  bf16x8_t bK0[4];       // B fragments kk=0 (live ph1 -> ph3)
  bf16x8_t bK1[4];       // B fragments kk=1 (live ph2 -> ph4)

#define RDA4(B, MH, CK)                                                       \
  aF[0] = *(const bf16x8_t*)&As[B][aRd + (MH) * 4096 + 0 * 1024 + (CK)];      \
  aF[1] = *(const bf16x8_t*)&As[B][aRd + (MH) * 4096 + 1 * 1024 + (CK)];      \
  aF[2] = *(const bf16x8_t*)&As[B][aRd + (MH) * 4096 + 2 * 1024 + (CK)];      \
  aF[3] = *(const bf16x8_t*)&As[B][aRd + (MH) * 4096 + 3 * 1024 + (CK)];
#define RDB4(B, DST, CK)                                                      \
  DST[0] = *(const bf16x8_t*)&Bs[B][bRd + 0 * 1024 + (CK)];                   \
  DST[1] = *(const bf16x8_t*)&Bs[B][bRd + 1 * 1024 + (CK)];                   \
  DST[2] = *(const bf16x8_t*)&Bs[B][bRd + 2 * 1024 + (CK)];                   \
  DST[3] = *(const bf16x8_t*)&Bs[B][bRd + 3 * 1024 + (CK)];

#define MFMAP(MH, BARR)                                                            \
  _Pragma("unroll")                                                                \
  for (int mi = 0; mi < 4; mi++) {                                                 \
    _Pragma("unroll")                                                              \
    for (int nf = 0; nf < 4; nf++) {                                               \
      acc[(MH) * 4 + mi][nf] = __builtin_amdgcn_mfma_f32_16x16x32_bf16(            \
          aF[mi], BARR[nf], acc[(MH) * 4 + mi][nf], 0, 0, 0);                      \
    }                                                                              \
  }

#define BAR() __builtin_amdgcn_s_barrier()
#define LGKM0()                                              \
  {                                                          \
    asm volatile("s_waitcnt lgkmcnt(0)" ::: "memory");       \
    __builtin_amdgcn_sched_barrier(0);                       \
  }
#define VMW(n)                                               \
  {                                                          \
    asm volatile("s_waitcnt vmcnt(" #n ")" ::: "memory");    \
    __builtin_amdgcn_sched_barrier(0);                       \
  }

  // TILE(T, BUF, OBUF, S1, S3, VMODE): BUF/OBUF literal 0/1.
  // VMODE 0 = VMW(2), 1 = VMW(0) drain, 2 = none.
#define TILE(T, BUF, OBUF, S1, S3, VMODE)                                \
  {                                                                      \
    /* ph1: mh0/kk0; stage B-both + A-late of (T+1) -> other buffer */   \
    RDA4(BUF, 0, ck0) RDB4(BUF, bK0, ck0)                                \
    if (S1) {                                                            \
      STB(OBUF, 0, ((T) + 1) * 64) STB(OBUF, 1, ((T) + 1) * 64)          \
      STA(OBUF, 1, ((T) + 1) * 64)                                       \
    }                                                                    \
    BAR(); LGKM0();                                                      \
    __builtin_amdgcn_s_setprio(1); MFMAP(0, bK0)                         \
    __builtin_amdgcn_s_setprio(0); BAR();                                \
    /* ph2: mh0/kk1 */                                                   \
    RDA4(BUF, 0, ck1) RDB4(BUF, bK1, ck1)                                \
    BAR(); LGKM0();                                                      \
    __builtin_amdgcn_s_setprio(1); MFMAP(0, bK1)                         \
    __builtin_amdgcn_s_setprio(0); BAR();                                \
    /* ph3: mh1/kk0 (bK0 reused); stage A-early(T+2) -> this buffer */   \
    RDA4(BUF, 1, ck0)                                                    \
    if (S3) { STA(BUF, 0, ((T) + 2) * 64) }                              \
    BAR(); LGKM0();                                                      \
    __builtin_amdgcn_s_setprio(1); MFMAP(1, bK0)                         \
    __builtin_amdgcn_s_setprio(0); BAR();                                \
    /* ph4: mh1/kk1 (bK1 reused); counted wait */                        \
    RDA4(BUF, 1, ck1)                                                    \
    if ((VMODE) == 0) { VMW(2); } else if ((VMODE) == 1) { VMW(0); }     \
    BAR(); LGKM0();                                                      \
    __builtin_amdgcn_s_setprio(1); MFMAP(1, bK1)                         \
    __builtin_amdgcn_s_setprio(0); BAR();                                \
  }

  // ---- prologue: tile0 (4 halves, buf0) + A-early(1) (buf1) = 10 gloads.
  // VMW(2) -> tile0's 8 complete (A-early(1) may stay in flight).
  STA(0, 0, 0) STA(0, 1, 0) STB(0, 0, 0) STB(0, 1, 0)
  STA(1, 0, 64)
  VMW(2);
  BAR();

  // nt = 32 K-tiles. Unrolled by 2 for literal buf. Full pipeline t<30;
  // t=30 stages tile31's B/A-late then drains; t=31 computes only.
  for (int t = 0; t < 30; t += 2) {
    TILE(t,     0, 1, 1, 1, 0)
    TILE(t + 1, 1, 0, 1, 1, 0)
  }
  TILE(30, 0, 1, 1, 0, 1)
  TILE(31, 1, 0, 0, 0, 2)

#undef TILE
#undef STA
#undef STB
#undef RDA4
#undef RDB4
#undef MFMAP
#undef BAR
#undef LGKM0
#undef VMW

  // epilogue: D row = fq*4 + r, col = fr (m89-verified C/D layout)
  const int mW = mBase + wm * 128 + fq * 4;
  const int nW = nBase + wn * 64 + fr;
#pragma unroll
  for (int f = 0; f < 8; f++) {
#pragma unroll
    for (int nf = 0; nf < 4; nf++) {
      const int n  = nW + nf * 16;
      const int m0 = mW + f * 16;
#pragma unroll
      for (int r = 0; r < 4; r++) {
        float v = acc[f][nf][r];
        size_t j = (size_t)(m0 + r) * N_DIM + n;
        if (EPI == 0) {
          Hout[j] = __float2bfloat16(fmaxf(v, 0.0f));
        } else {
          unsigned bits = threefry_mask_bits((unsigned)j);
          float y  = (bits < 0xC0000000u) ? v * (1.0f / 0.75f) : 0.0f;
          Fout[j]  = __bfloat162float(Xn[j]) + y;
        }
      }
    }
  }
}

extern "C" void kernel_launch(void* const* d_in, const int* in_sizes, int n_in,
                              void* d_out, int out_size, void* d_ws, size_t ws_size,
                              hipStream_t stream) {
  (void)in_sizes; (void)n_in; (void)out_size; (void)ws_size;
  const float* X  = (const float*)d_in[0];
  const float* W1 = (const float*)d_in[1];
  const float* W2 = (const float*)d_in[2];
  float* out = (float*)d_out;

  unsigned char* ws = (unsigned char*)d_ws;
  __hip_bfloat16* Xn  = (__hip_bfloat16*)(ws);                       // 32 MB
  __hip_bfloat16* H   = (__hip_bfloat16*)(ws + ((size_t)32 << 20));  // 32 MB
  __hip_bfloat16* W1t = (__hip_bfloat16*)(ws + ((size_t)64 << 20));  //  8 MB
  __hip_bfloat16* W2t = (__hip_bfloat16*)(ws + ((size_t)72 << 20));  //  8 MB

  wt_kernel<<<dim3(64, 64, 2), dim3(32, 8, 1), 0, stream>>>(W1, W2, W1t, W2t);
  ln_kernel<<<M_DIM, 256, 0, stream>>>(X, Xn);
  gemm256<0><<<dim3(256, 1, 1), dim3(512, 1, 1), 0, stream>>>(Xn, W1t, nullptr, H, nullptr);
  gemm256<1><<<dim3(256, 1, 1), dim3(512, 1, 1), 0, stream>>>(H, W2t, Xn, nullptr, out);
}

// Round 4
// 341.767 us; speedup vs baseline: 1.0021x; 1.0009x over previous
//
#include <hip/hip_runtime.h>
#include <hip/hip_bf16.h>
#include <stdint.h>

// Problem: out = x_norm + dropout(relu(LN(x) @ W1) @ W2), B=4,S=2048,D=2048
#define M_DIM 8192   // B*S
#define N_DIM 2048
#define K_DIM 2048

typedef __bf16 bf16x8_t __attribute__((ext_vector_type(8)));
typedef float f32x4_t __attribute__((ext_vector_type(4)));

// ---------------- threefry2x32, JAX partitionable path, key=(0,1) -------------
// bits(j) = o0^o1 of threefry2x32(key=(0,1), ctr=(0, j)); keep iff bits < 0xC0000000.
// Verified: absmax 0.0625 -> mask exact.
__device__ __forceinline__ unsigned tf_rotl(unsigned x, int r) {
  return (x << r) | (x >> (32 - r));
}
__device__ __forceinline__ unsigned threefry_mask_bits(unsigned ctr) {
  unsigned x0 = 0u, x1 = ctr;
  const unsigned ks0 = 0u, ks1 = 1u, ks2 = 0x1BD11BDBu;
  x0 += ks0; x1 += ks1;
#define TFR(r) { x0 += x1; x1 = tf_rotl(x1, (r)); x1 ^= x0; }
  TFR(13) TFR(15) TFR(26) TFR(6)
  x0 += ks1; x1 += ks2 + 1u;
  TFR(17) TFR(29) TFR(16) TFR(24)
  x0 += ks2; x1 += ks0 + 2u;
  TFR(13) TFR(15) TFR(26) TFR(6)
  x0 += ks0; x1 += ks1 + 3u;
  TFR(17) TFR(29) TFR(16) TFR(24)
  x0 += ks1; x1 += ks2 + 4u;
  TFR(13) TFR(15) TFR(26) TFR(6)
  x0 += ks2; x1 += ks0 + 5u;
#undef TFR
  return x0 ^ x1;
}

// ---------------- async global->LDS, 16B per lane -----------------------------
__device__ __forceinline__ void gload_lds16(const __hip_bfloat16* g, unsigned short* l) {
  __builtin_amdgcn_global_load_lds(
      (const __attribute__((address_space(1))) unsigned int*)g,
      (__attribute__((address_space(3))) unsigned int*)l,
      16, 0, 0);
}

// ---------------- W [K][N] fp32 -> Wt [N][K] bf16 -----------------------------
__global__ __launch_bounds__(256) void wt_kernel(
    const float* __restrict__ W1, const float* __restrict__ W2,
    __hip_bfloat16* __restrict__ W1t, __hip_bfloat16* __restrict__ W2t) {
  __shared__ float tile[32][33];
  const float* src = blockIdx.z ? W2 : W1;
  __hip_bfloat16* dst = blockIdx.z ? W2t : W1t;
  int x = blockIdx.x * 32 + threadIdx.x;
  int y = blockIdx.y * 32 + threadIdx.y;
#pragma unroll
  for (int i = 0; i < 32; i += 8)
    tile[threadIdx.y + i][threadIdx.x] = src[(size_t)(y + i) * N_DIM + x];
  __syncthreads();
  int xo = blockIdx.y * 32 + threadIdx.x;
  int yo = blockIdx.x * 32 + threadIdx.y;
#pragma unroll
  for (int i = 0; i < 32; i += 8)
    dst[(size_t)(yo + i) * K_DIM + xo] = __float2bfloat16(tile[threadIdx.x][threadIdx.y + i]);
}

// ---------------- LayerNorm (no affine) -> bf16 -------------------------------
__global__ __launch_bounds__(256) void ln_kernel(const float* __restrict__ X,
                                                 __hip_bfloat16* __restrict__ Xn) {
  const int row = blockIdx.x;
  const float4* xv = (const float4*)(X + (size_t)row * K_DIM);
  float4 v0 = xv[threadIdx.x];
  float4 v1 = xv[threadIdx.x + 256];
  float s  = v0.x + v0.y + v0.z + v0.w + v1.x + v1.y + v1.z + v1.w;
  float ss = v0.x*v0.x + v0.y*v0.y + v0.z*v0.z + v0.w*v0.w
           + v1.x*v1.x + v1.y*v1.y + v1.z*v1.z + v1.w*v1.w;
#pragma unroll
  for (int off = 32; off > 0; off >>= 1) {
    s  += __shfl_xor(s, off);
    ss += __shfl_xor(ss, off);
  }
  __shared__ float rs[4], rss[4];
  const int wave = threadIdx.x >> 6;
  if ((threadIdx.x & 63) == 0) { rs[wave] = s; rss[wave] = ss; }
  __syncthreads();
  float S  = rs[0] + rs[1] + rs[2] + rs[3];
  float SS = rss[0] + rss[1] + rss[2] + rss[3];
  float mean = S * (1.0f / 2048.0f);
  float var  = SS * (1.0f / 2048.0f) - mean * mean;
  float rstd = 1.0f / sqrtf(var + 1e-6f);
  float vv[8] = {v0.x, v0.y, v0.z, v0.w, v1.x, v1.y, v1.z, v1.w};
  unsigned short o[8];
#pragma unroll
  for (int i = 0; i < 8; i++) {
    __hip_bfloat16 b = __float2bfloat16((vv[i] - mean) * rstd);
    o[i] = *(unsigned short*)&b;
  }
  ushort4* dst = (ushort4*)(Xn + (size_t)row * K_DIM);
  dst[threadIdx.x]       = make_ushort4(o[0], o[1], o[2], o[3]);
  dst[threadIdx.x + 256] = make_ushort4(o[4], o[5], o[6], o[7]);
}

// ---------------- 256x256 MFMA GEMM, BK=64, 8-phase counted-vmcnt schedule ----
// A[M][K], Bt[N][K] bf16. 512 threads = 8 waves (2M x 4N), per-wave 128x64 out.
// LDS: 2 x (A 256x64 + B 256x64) bf16 = 128 KB, double-buffered by K-tile.
// Round-3 post-mortem: WRITE_SIZE 262 MB / FETCH 185 MB byte-identical across
// two different register structures, VGPR pegged at 128 (=256 cap minus 128
// AGPR acc) -> scratch spills caused by the ~160 sched_barrier(0)s pinning the
// scheduler into tiny regions (m141 signature), not by fragment liveness.
// Rule #18 does NOT apply: ds_reads here are compiler-visible C++ loads, so
// RAW ds_read->MFMA waits are compiler-inserted. This version = round 3 with
// ALL sched_barrier(0) removed; "memory" clobbers kept on waitcnt asm (they
// fence ds_reads from sinking past phase boundaries into staging regions).
// Phase split by (m-half, kk): per phase 4 A-frags (phase-local) + 4 B-frags
// per kk (bK0 live ph1->ph3, bK1 ph2->ph4). 24 ds_read_b128/tile. K-loop
// unrolled by 2 so buf is a literal.
// Region/reader map (kk split => every B row read every phase):
//   A-early rows {0-63,128-191}: read ph1,ph2  -> stage(t+2) at ph3 (cur buf)
//   A-late  rows {64-127,192-255}: read ph3,ph4 -> stage(t+1) at ph1 (other buf)
//   B (all rows): read every phase             -> stage(t+1) at ph1 (other buf)
// Issues: ph1 6 gloads, ph3 2 gloads. VMW(2) at ph4 leaves only ph3's
// A-early(t+2) in flight => everything tile t+1 reads is complete before the
// ph4 trailing barrier. Drain vmcnt(0) only at t=30. Raw s_barrier throughout
// (__syncthreads would drain vmcnt and kill the pipeline). Per-acc-element
// MFMA order kk0 then kk1 per tile -> bit-identical to the 110 us kernel.
// EPI=0: H=relu(A@B)->bf16. EPI=1: out=Xn+dropout(A@B)/0.75.
template <int EPI>
__global__ __launch_bounds__(512, 2) void gemm256(
    const __hip_bfloat16* __restrict__ A,
    const __hip_bfloat16* __restrict__ Bt,
    const __hip_bfloat16* __restrict__ Xn,   // EPI=1 residual
    __hip_bfloat16* __restrict__ Hout,       // EPI=0 output
    float* __restrict__ Fout) {              // EPI=1 output
  __shared__ unsigned short As[2][16384];  // 2 x 32 KB
  __shared__ unsigned short Bs[2][16384];  // 2 x 32 KB
  const int tid  = threadIdx.x;
  const int lane = tid & 63;
  const int wave = tid >> 6;      // 0..7
  const int wm = wave >> 2;       // 0..1 (M)
  const int wn = wave & 3;        // 0..3 (N)

  // XCD-aware swizzle: nwg=256 (divisible by 8) -> XCD x owns all 32 M-tiles
  // of one N-column -> 1 MB B panel L2-resident per XCD.
  const int bid = blockIdx.x;
  const int wg  = (bid & 7) * 32 + (bid >> 3);
  const int mBase = (wg & 31) << 8;   // 32 M-tiles, fastest
  const int nBase = (wg >> 5) << 8;   // 8 N-tiles

  f32x4_t acc[8][4];
#pragma unroll
  for (int i = 0; i < 8; i++)
#pragma unroll
    for (int j = 0; j < 4; j++) acc[i][j] = (f32x4_t){0.f, 0.f, 0.f, 0.f};

  // ---- staging addresses. Half-tile = 128 rows x 128 B = 2 gloads/thread.
  // Wave w covers 8 rows/gload; lane l: row l>>3, source chunk (l&7)^(row&7).
  const int rowIn = lane >> 3;
  const int csrc  = ((lane & 7) ^ (rowIn & 7)) << 3;   // swizzled src elem offset
  const __hip_bfloat16* aSrcB = A  + (size_t)(mBase + 8 * wave + rowIn) * K_DIM + csrc;
  const int bRowW = ((wave >> 2) << 6) + ((wave & 3) << 3);
  const __hip_bfloat16* bSrcB = Bt + (size_t)(nBase + bRowW + rowIn) * K_DIM + csrc;
  const int aDst = wave << 9;     // shorts; wave-uniform base, HW adds lane*16B
  const int bDst = bRowW << 6;

  // A half h: rows h*64 + {0,128} + 8w + rowIn  (h=0 early, h=1 late)
  // B half h: rows h*32 + {0,128} + bRowW + rowIn
#define STA(b, h, k)                                                                         \
  gload_lds16(aSrcB + (size_t)((h) * 64) * K_DIM + (k), &As[b][aDst + (h) * 4096]);          \
  gload_lds16(aSrcB + (size_t)((h) * 64 + 128) * K_DIM + (k), &As[b][aDst + (h) * 4096 + 8192]);
#define STB(b, h, k)                                                                         \
  gload_lds16(bSrcB + (size_t)((h) * 32) * K_DIM + (k), &Bs[b][bDst + (h) * 2048]);          \
  gload_lds16(bSrcB + (size_t)((h) * 32 + 128) * K_DIM + (k), &Bs[b][bDst + (h) * 2048 + 8192]);

  // ---- fragment read addresses (static swizzle: slot = chunk ^ (row&7))
  const int fr = lane & 15;
  const int fq = lane >> 4;
  const int ck0 = ((fq)     ^ (fr & 7)) << 3;   // kk=0 chunk offset (shorts)
  const int ck1 = ((4 | fq) ^ (fr & 7)) << 3;   // kk=1 chunk offset
  const int aRd = (wm * 128 + fr) * 64;
  const int bRd = (wn * 64  + fr) * 64;

  bf16x8_t aF[4];        // per-phase A fragments (phase-local)
  bf16x8_t bK0[4];       // B fragments kk=0 (live ph1 -> ph3)
  bf16x8_t bK1[4];       // B fragments kk=1 (live ph2 -> ph4)

#define RDA4(B, MH, CK)                                                       \
  aF[0] = *(const bf16x8_t*)&As[B][aRd + (MH) * 4096 + 0 * 1024 + (CK)];      \
  aF[1] = *(const bf16x8_t*)&As[B][aRd + (MH) * 4096 + 1 * 1024 + (CK)];      \
  aF[2] = *(const bf16x8_t*)&As[B][aRd + (MH) * 4096 + 2 * 1024 + (CK)];      \
  aF[3] = *(const bf16x8_t*)&As[B][aRd + (MH) * 4096 + 3 * 1024 + (CK)];
#define RDB4(B, DST, CK)                                                      \
  DST[0] = *(const bf16x8_t*)&Bs[B][bRd + 0 * 1024 + (CK)];                   \
  DST[1] = *(const bf16x8_t*)&Bs[B][bRd + 1 * 1024 + (CK)];                   \
  DST[2] = *(const bf16x8_t*)&Bs[B][bRd + 2 * 1024 + (CK)];                   \
  DST[3] = *(const bf16x8_t*)&Bs[B][bRd + 3 * 1024 + (CK)];

#define MFMAP(MH, BARR)                                                            \
  _Pragma("unroll")                                                                \
  for (int mi = 0; mi < 4; mi++) {                                                 \
    _Pragma("unroll")                                                              \
    for (int nf = 0; nf < 4; nf++) {                                               \
      acc[(MH) * 4 + mi][nf] = __builtin_amdgcn_mfma_f32_16x16x32_bf16(            \
          aF[mi], BARR[nf], acc[(MH) * 4 + mi][nf], 0, 0, 0);                      \
    }                                                                              \
  }

#define BAR() __builtin_amdgcn_s_barrier()
#define LGKM0() asm volatile("s_waitcnt lgkmcnt(0)" ::: "memory")
#define VMW(n)  asm volatile("s_waitcnt vmcnt(" #n ")" ::: "memory")

  // TILE(T, BUF, OBUF, S1, S3, VMODE): BUF/OBUF literal 0/1.
  // VMODE 0 = VMW(2), 1 = VMW(0) drain, 2 = none.
#define TILE(T, BUF, OBUF, S1, S3, VMODE)                                \
  {                                                                      \
    /* ph1: mh0/kk0; stage B-both + A-late of (T+1) -> other buffer */   \
    RDA4(BUF, 0, ck0) RDB4(BUF, bK0, ck0)                                \
    if (S1) {                                                            \
      STB(OBUF, 0, ((T) + 1) * 64) STB(OBUF, 1, ((T) + 1) * 64)          \
      STA(OBUF, 1, ((T) + 1) * 64)                                       \
    }                                                                    \
    BAR(); LGKM0();                                                      \
    __builtin_amdgcn_s_setprio(1); MFMAP(0, bK0)                         \
    __builtin_amdgcn_s_setprio(0); BAR();                                \
    /* ph2: mh0/kk1 */                                                   \
    RDA4(BUF, 0, ck1) RDB4(BUF, bK1, ck1)                                \
    BAR(); LGKM0();                                                      \
    __builtin_amdgcn_s_setprio(1); MFMAP(0, bK1)                         \
    __builtin_amdgcn_s_setprio(0); BAR();                                \
    /* ph3: mh1/kk0 (bK0 reused); stage A-early(T+2) -> this buffer */   \
    RDA4(BUF, 1, ck0)                                                    \
    if (S3) { STA(BUF, 0, ((T) + 2) * 64) }                              \
    BAR(); LGKM0();                                                      \
    __builtin_amdgcn_s_setprio(1); MFMAP(1, bK0)                         \
    __builtin_amdgcn_s_setprio(0); BAR();                                \
    /* ph4: mh1/kk1 (bK1 reused); counted wait */                        \
    RDA4(BUF, 1, ck1)                                                    \
    if ((VMODE) == 0) { VMW(2); } else if ((VMODE) == 1) { VMW(0); }     \
    BAR(); LGKM0();                                                      \
    __builtin_amdgcn_s_setprio(1); MFMAP(1, bK1)                         \
    __builtin_amdgcn_s_setprio(0); BAR();                                \
  }

  // ---- prologue: tile0 (4 halves, buf0) + A-early(1) (buf1) = 10 gloads.
  // VMW(2) -> tile0's 8 complete (A-early(1) may stay in flight).
  STA(0, 0, 0) STA(0, 1, 0) STB(0, 0, 0) STB(0, 1, 0)
  STA(1, 0, 64)
  VMW(2);
  BAR();

  // nt = 32 K-tiles. Unrolled by 2 for literal buf. Full pipeline t<30;
  // t=30 stages tile31's B/A-late then drains; t=31 computes only.
  for (int t = 0; t < 30; t += 2) {
    TILE(t,     0, 1, 1, 1, 0)
    TILE(t + 1, 1, 0, 1, 1, 0)
  }
  TILE(30, 0, 1, 1, 0, 1)
  TILE(31, 1, 0, 0, 0, 2)

#undef TILE
#undef STA
#undef STB
#undef RDA4
#undef RDB4
#undef MFMAP
#undef BAR
#undef LGKM0
#undef VMW

  // epilogue: D row = fq*4 + r, col = fr (m89-verified C/D layout)
  const int mW = mBase + wm * 128 + fq * 4;
  const int nW = nBase + wn * 64 + fr;
#pragma unroll
  for (int f = 0; f < 8; f++) {
#pragma unroll
    for (int nf = 0; nf < 4; nf++) {
      const int n  = nW + nf * 16;
      const int m0 = mW + f * 16;
#pragma unroll
      for (int r = 0; r < 4; r++) {
        float v = acc[f][nf][r];
        size_t j = (size_t)(m0 + r) * N_DIM + n;
        if (EPI == 0) {
          Hout[j] = __float2bfloat16(fmaxf(v, 0.0f));
        } else {
          unsigned bits = threefry_mask_bits((unsigned)j);
          float y  = (bits < 0xC0000000u) ? v * (1.0f / 0.75f) : 0.0f;
          Fout[j]  = __bfloat162float(Xn[j]) + y;
        }
      }
    }
  }
}

extern "C" void kernel_launch(void* const* d_in, const int* in_sizes, int n_in,
                              void* d_out, int out_size, void* d_ws, size_t ws_size,
                              hipStream_t stream) {
  (void)in_sizes; (void)n_in; (void)out_size; (void)ws_size;
  const float* X  = (const float*)d_in[0];
  const float* W1 = (const float*)d_in[1];
  const float* W2 = (const float*)d_in[2];
  float* out = (float*)d_out;

  unsigned char* ws = (unsigned char*)d_ws;
  __hip_bfloat16* Xn  = (__hip_bfloat16*)(ws);                       // 32 MB
  __hip_bfloat16* H   = (__hip_bfloat16*)(ws + ((size_t)32 << 20));  // 32 MB
  __hip_bfloat16* W1t = (__hip_bfloat16*)(ws + ((size_t)64 << 20));  //  8 MB
  __hip_bfloat16* W2t = (__hip_bfloat16*)(ws + ((size_t)72 << 20));  //  8 MB

  wt_kernel<<<dim3(64, 64, 2), dim3(32, 8, 1), 0, stream>>>(W1, W2, W1t, W2t);
  ln_kernel<<<M_DIM, 256, 0, stream>>>(X, Xn);
  gemm256<0><<<dim3(256, 1, 1), dim3(512, 1, 1), 0, stream>>>(Xn, W1t, nullptr, H, nullptr);
  gemm256<1><<<dim3(256, 1, 1), dim3(512, 1, 1), 0, stream>>>(H, W2t, Xn, nullptr, out);
}